// Round 17
// baseline (282.391 us; speedup 1.0000x reference)
//
#include <hip/hip_runtime.h>
#include <math.h>

#define D_MODEL 1024
#define D_STATE 8
#define D_CONV  4
#define D_INNER 1536
#define DT_RANK 64
#define D_FF    2048
#define BATCH   2
#define SEQ     2048
#define NROWS   (BATCH*SEQ)      // 4096
#define NC      32               // scan chunks
#define LC      (SEQ/NC)         // 64
#define XQW     512              // interleaved x_dbl partial width (4 x 128)

typedef short bf16x8 __attribute__((ext_vector_type(8)));
typedef unsigned short u16x8 __attribute__((ext_vector_type(8)));
typedef float f32x4  __attribute__((ext_vector_type(4)));

__device__ inline unsigned short f2bf(float x) {
    union { float f; unsigned u; } v; v.f = x;
    unsigned r = v.u + 0x7fffu + ((v.u >> 16) & 1u);
    return (unsigned short)(r >> 16);
}
__device__ inline float bf2f(unsigned short h) {
    union { unsigned u; float f; } v; v.u = ((unsigned)h) << 16;
    return v.f;
}
__device__ inline float softplus_f(float x) {
    return (x > 20.0f) ? x : log1pf(__expf(x));
}
__device__ inline float gelu_f(float x) {
    return 0.5f * x * (1.0f + erff(x * 0.70710678118654752f));
}
__device__ inline float silu_f(float x) {
    return x / (1.0f + __expf(-x));
}
__device__ inline void gload16(const unsigned short* g, unsigned short* l) {
    typedef unsigned int u32;
    __builtin_amdgcn_global_load_lds(
        (const __attribute__((address_space(1))) u32*)g,
        (__attribute__((address_space(3))) u32*)l, 16, 0, 0);
}

#define PHASE_SYNC_PRE()  do { __builtin_amdgcn_s_barrier(); \
                               asm volatile("s_waitcnt lgkmcnt(0)" ::: "memory"); } while (0)
#define PHASE_SYNC_POST() do { __builtin_amdgcn_s_barrier(); } while (0)

// ---------------- prep: weight conversions + xproj pad + LN1 ----------------
__global__ __launch_bounds__(256) void prep_kernel(
    const float* __restrict__ s0, unsigned short* __restrict__ d0,
    const float* __restrict__ s1, unsigned short* __restrict__ d1,
    const float* __restrict__ s2, unsigned short* __restrict__ d2,
    const float* __restrict__ s3, unsigned short* __restrict__ d3,
    const float* __restrict__ s4, unsigned short* __restrict__ d4,
    const float* __restrict__ xpw, unsigned short* __restrict__ xpd,
    const float* __restrict__ x, const float* __restrict__ g1,
    const float* __restrict__ b1, unsigned short* __restrict__ xout) {
    int b = blockIdx.x;
    if (b < 4400) {
        const float* s; unsigned short* d; int base;
        if      (b < 1536) { s = s0; d = d0; base = b * 2048; }
        else if (b < 1584) { s = s1; d = d1; base = (b - 1536) * 2048; }
        else if (b < 2352) { s = s2; d = d2; base = (b - 1584) * 2048; }
        else if (b < 3376) { s = s3; d = d3; base = (b - 2352) * 2048; }
        else               { s = s4; d = d4; base = (b - 3376) * 2048; }
        int i = base + threadIdx.x * 8;
        float4 v0 = *(const float4*)(s + i);
        float4 v1 = *(const float4*)(s + i + 4);
        ushort4 a, c;
        a.x = f2bf(v0.x); a.y = f2bf(v0.y); a.z = f2bf(v0.z); a.w = f2bf(v0.w);
        c.x = f2bf(v1.x); c.y = f2bf(v1.y); c.z = f2bf(v1.z); c.w = f2bf(v1.w);
        *(ushort4*)(d + i)     = a;
        *(ushort4*)(d + i + 4) = c;
    } else if (b < 4528) {
        int row = b - 4400;
        for (int c = threadIdx.x; c < D_INNER; c += 256)
            xpd[row * D_INNER + c] = (row < 80) ? f2bf(xpw[row * D_INNER + c]) : (unsigned short)0;
    } else {
        __shared__ float sbuf[4];
        int row = b - 4528;
        int t = threadIdx.x;
        float4 v = ((const float4*)(x + (size_t)row * D_MODEL))[t];
        float s = v.x + v.y + v.z + v.w;
        for (int o = 32; o; o >>= 1) s += __shfl_down(s, o, 64);
        if ((t & 63) == 0) sbuf[t >> 6] = s;
        __syncthreads();
        float mu = (sbuf[0] + sbuf[1] + sbuf[2] + sbuf[3]) * (1.0f / D_MODEL);
        __syncthreads();
        float e0 = v.x - mu, e1 = v.y - mu, e2 = v.z - mu, e3 = v.w - mu;
        float q = e0*e0 + e1*e1 + e2*e2 + e3*e3;
        for (int o = 32; o; o >>= 1) q += __shfl_down(q, o, 64);
        if ((t & 63) == 0) sbuf[t >> 6] = q;
        __syncthreads();
        float var = (sbuf[0] + sbuf[1] + sbuf[2] + sbuf[3]) * (1.0f / D_MODEL);
        float rs = rsqrtf(var + 1e-5f);
        float4 gv = ((const float4*)g1)[t];
        float4 bv = ((const float4*)b1)[t];
        ushort4 st;
        st.x = f2bf(e0 * rs * gv.x + bv.x);
        st.y = f2bf(e1 * rs * gv.y + bv.y);
        st.z = f2bf(e2 * rs * gv.z + bv.z);
        st.w = f2bf(e3 * rs * gv.w + bv.w);
        ((ushort4*)(xout + (size_t)row * D_MODEL))[t] = st;
    }
}

// ---------------- epilogue IDs ----------------
#define EPI_F32        0
#define EPI_GELU_BF16  4
#define EPI_BF16       6
#define EPI_SOFTPLUS_BF16 7
#define EPI_PBF16      9

// ================= 256-row MFMA GEMM (NT), PH=8 or PH=4 =================
template<int WN, int EPI, int SPLITK, int PH>
__global__ __launch_bounds__(512, 2) void gemm8p(
    const unsigned short* __restrict__ A, int lda,
    const unsigned short* __restrict__ Bm, int ldb, int K,
    float* __restrict__ Cf, unsigned short* __restrict__ Cb, int ldc,
    const float* __restrict__ bias,
    const float* __restrict__ resid, int ldr) {
    constexpr int WM = 8 / WN;
    constexpr int BN = WN * 64;
    constexpr int RW = 256 / WM;
    constexpr int CW = 64;
    constexpr int MI = RW / 16;
    constexpr int NI = CW / 16;
    constexpr int MIH = MI / 2, NIH = NI / 2;
    constexpr int ABYTES = 256 * 128;
    constexpr int BBYTES = BN * 128;
    constexpr int BOFF = 2 * ABYTES;
    __shared__ unsigned short lds[(2 * ABYTES + 2 * BBYTES) / 2];

    const int t = threadIdx.x, l = t & 63, w = t >> 6;
    const int wr = w / WN, wc = w % WN;

    const int nx = gridDim.x;
    const int nwg = nx * gridDim.y;
    int bid = blockIdx.y * nx + blockIdx.x;
    int q = nwg >> 3;
    int swz = (bid & 7) * q + (bid >> 3);
    const int m0 = (swz / nx) * 256, n0 = (swz % nx) * BN;
    const int kbase = (SPLITK > 1) ? blockIdx.z * K : 0;

    const int sr = l >> 3;
    const int sj = ((l & 7) * 16) ^ ((l >> 3) << 4);
    const int row_l = w * 8;
    const int row_c = (w >> 2) * 64 + (w & 3) * 8;

    auto STG = [&](int bufbyte, int rowbase, const unsigned short* G, int ldg, int gbase, int kt) {
        unsigned short* dst = (unsigned short*)((char*)lds + bufbyte + rowbase * 128);
        const unsigned short* src = G + (size_t)(gbase + rowbase + sr) * ldg + kbase + kt * 64 + (sj >> 1);
        gload16(src, dst);
    };
    auto S_Ah0 = [&](int b, int kt) {
        if (WN == 4) { STG(b * ABYTES, row_l, A, lda, m0, kt);       STG(b * ABYTES, 128 + row_l, A, lda, m0, kt); }
        else         { STG(b * ABYTES, row_c, A, lda, m0, kt);       STG(b * ABYTES, 128 + row_c, A, lda, m0, kt); }
    };
    auto S_Ah1 = [&](int b, int kt) {
        if (WN == 4) { STG(b * ABYTES, 64 + row_l, A, lda, m0, kt);  STG(b * ABYTES, 192 + row_l, A, lda, m0, kt); }
        else         { STG(b * ABYTES, 32 + row_c, A, lda, m0, kt);  STG(b * ABYTES, 160 + row_c, A, lda, m0, kt); }
    };
    auto S_Bc0 = [&](int b, int kt) {
        if (WN == 4) { STG(BOFF + b * BBYTES, row_c, Bm, ldb, n0, kt); STG(BOFF + b * BBYTES, 128 + row_c, Bm, ldb, n0, kt); }
        else         { STG(BOFF + b * BBYTES, row_c, Bm, ldb, n0, kt); }
    };
    auto S_Bc1 = [&](int b, int kt) {
        if (WN == 4) { STG(BOFF + b * BBYTES, 32 + row_c, Bm, ldb, n0, kt); STG(BOFF + b * BBYTES, 160 + row_c, Bm, ldb, n0, kt); }
        else         { STG(BOFF + b * BBYTES, 32 + row_c, Bm, ldb, n0, kt); }
    };

    auto LD = [&](int bytebase, int row, int kb) -> bf16x8 {
        int o = bytebase + row * 128 + (kb ^ ((row & 7) << 4));
        return *(const bf16x8*)((const char*)lds + o);
    };

    f32x4 acc[MI][NI] = {};
    bf16x8 af[MIH][2], b0v[NIH][2], b1v[NIH][2];

    auto LDA_set = [&](int buf, int qr, auto& dst) {
        #pragma unroll
        for (int mi = 0; mi < MIH; mi++)
            #pragma unroll
            for (int ks = 0; ks < 2; ks++)
                dst[mi][ks] = LD(buf * ABYTES, wr * RW + qr * (RW / 2) + mi * 16 + (l & 15),
                                 ks * 64 + (l >> 4) * 16);
    };
    auto LDB_set = [&](int buf, int qc, auto& dst) {
        #pragma unroll
        for (int ni2 = 0; ni2 < NIH; ni2++)
            #pragma unroll
            for (int ks = 0; ks < 2; ks++)
                dst[ni2][ks] = LD(BOFF + buf * BBYTES, wc * CW + qc * 32 + ni2 * 16 + (l & 15),
                                  ks * 64 + (l >> 4) * 16);
    };
    auto MFMA_Q = [&](int qr, int qc, auto& a_, auto& b_) {
        __builtin_amdgcn_s_setprio(1);
        #pragma unroll
        for (int mi = 0; mi < MIH; mi++)
            #pragma unroll
            for (int ni2 = 0; ni2 < NIH; ni2++)
                #pragma unroll
                for (int ks = 0; ks < 2; ks++)
                    acc[qr * MIH + mi][qc * NIH + ni2] =
                        __builtin_amdgcn_mfma_f32_16x16x32_bf16(a_[mi][ks], b_[ni2][ks],
                                                                acc[qr * MIH + mi][qc * NIH + ni2], 0, 0, 0);
        __builtin_amdgcn_s_setprio(0);
    };
    auto VMW8 = [&](bool last) {
        if (last)            asm volatile("s_waitcnt vmcnt(0)" ::: "memory");
        else if (WN == 4)    asm volatile("s_waitcnt vmcnt(6)" ::: "memory");
        else                 asm volatile("s_waitcnt vmcnt(5)" ::: "memory");
    };
    auto VMW4 = [&](bool last) {
        if (last)            asm volatile("s_waitcnt vmcnt(0)" ::: "memory");
        else if (WN == 4)    asm volatile("s_waitcnt vmcnt(4)" ::: "memory");
        else                 asm volatile("s_waitcnt vmcnt(3)" ::: "memory");
    };

    const int ni_ = K >> 7;

    S_Ah0(0, 0); S_Ah1(0, 0); S_Bc0(0, 0); S_Bc1(0, 0);
    S_Ah0(1, 1); S_Ah1(1, 1); S_Bc0(1, 1); S_Bc1(1, 1);
    if (WN == 4) asm volatile("s_waitcnt vmcnt(8)" ::: "memory");
    else         asm volatile("s_waitcnt vmcnt(6)" ::: "memory");
    __builtin_amdgcn_s_barrier();

    if constexpr (PH == 8) {
        for (int i = 0; i < ni_; i++) {
            const bool last = (i == ni_ - 1);
            const int t2 = 2 * i + 2, t3 = 2 * i + 3;
            LDA_set(0, 0, af); LDB_set(0, 0, b0v);
            if (i) S_Bc0(1, 2 * i + 1);
            PHASE_SYNC_PRE(); MFMA_Q(0, 0, af, b0v); PHASE_SYNC_POST();
            LDB_set(0, 1, b1v);
            if (!last) S_Ah0(0, t2);
            PHASE_SYNC_PRE(); MFMA_Q(0, 1, af, b1v); PHASE_SYNC_POST();
            LDA_set(0, 1, af);
            PHASE_SYNC_PRE(); MFMA_Q(1, 1, af, b1v); PHASE_SYNC_POST();
            LDB_set(0, 0, b0v);
            if (!last) { S_Ah1(0, t2); S_Bc1(0, t2); }
            VMW8(last);
            PHASE_SYNC_PRE(); MFMA_Q(1, 0, af, b0v); PHASE_SYNC_POST();
            LDA_set(1, 0, af); LDB_set(1, 0, b0v);
            if (!last) S_Bc0(0, t2);
            PHASE_SYNC_PRE(); MFMA_Q(0, 0, af, b0v); PHASE_SYNC_POST();
            LDB_set(1, 1, b1v);
            if (!last) S_Ah0(1, t3);
            PHASE_SYNC_PRE(); MFMA_Q(0, 1, af, b1v); PHASE_SYNC_POST();
            LDA_set(1, 1, af);
            PHASE_SYNC_PRE(); MFMA_Q(1, 1, af, b1v); PHASE_SYNC_POST();
            LDB_set(1, 0, b0v);
            if (!last) { S_Ah1(1, t3); S_Bc1(1, t3); }
            VMW8(last);
            PHASE_SYNC_PRE(); MFMA_Q(1, 0, af, b0v); PHASE_SYNC_POST();
        }
    } else {
        for (int i = 0; i < ni_; i++) {
            const bool last = (i == ni_ - 1);
            const int t2 = 2 * i + 2, t3 = 2 * i + 3;
            LDA_set(0, 0, af); LDB_set(0, 0, b0v); LDB_set(0, 1, b1v);
            if (i) { S_Bc0(1, 2 * i + 1); S_Ah1(1, 2 * i + 1); }
            PHASE_SYNC_PRE();
            MFMA_Q(0, 0, af, b0v); MFMA_Q(0, 1, af, b1v);
            PHASE_SYNC_POST();
            LDA_set(0, 1, af);
            if (!last) { S_Ah0(0, t2); S_Bc1(0, t2); }
            VMW4(last);
            PHASE_SYNC_PRE();
            MFMA_Q(1, 1, af, b1v); MFMA_Q(1, 0, af, b0v);
            PHASE_SYNC_POST();
            LDA_set(1, 0, af); LDB_set(1, 0, b0v); LDB_set(1, 1, b1v);
            if (!last) { S_Bc0(0, t2); S_Ah1(0, t2); }
            PHASE_SYNC_PRE();
            MFMA_Q(0, 0, af, b0v); MFMA_Q(0, 1, af, b1v);
            PHASE_SYNC_POST();
            LDA_set(1, 1, af);
            if (!last) { S_Ah0(1, t3); S_Bc1(1, t3); }
            VMW4(last);
            PHASE_SYNC_PRE();
            MFMA_Q(1, 1, af, b1v); MFMA_Q(1, 0, af, b0v);
            PHASE_SYNC_POST();
        }
    }

    float* Cfp = Cf;
    unsigned short* Cbp = Cb;
    if (SPLITK > 1) {
        Cfp += (size_t)blockIdx.z * NROWS * ldc;
        Cbp += (size_t)blockIdx.z * NROWS * ldc;
    }
    #pragma unroll
    for (int ni2 = 0; ni2 < NI; ni2++) {
        int col = n0 + wc * CW + ni2 * 16 + (l & 15);
        float bv = 0.0f;
        if (EPI == EPI_GELU_BF16) bv = bias[col];
        #pragma unroll
        for (int mi = 0; mi < MI; mi++) {
            #pragma unroll
            for (int j = 0; j < 4; j++) {
                int row = m0 + wr * RW + mi * 16 + (l >> 4) * 4 + j;
                float v = acc[mi][ni2][j];
                if (EPI == EPI_GELU_BF16)  v = gelu_f(v + bv);
                if (EPI == EPI_GELU_BF16 || EPI == EPI_BF16 || EPI == EPI_PBF16) {
                    Cbp[(size_t)row * ldc + col] = f2bf(v);
                } else {
                    Cfp[(size_t)row * ldc + col] = v;
                }
            }
        }
    }
}

// ---------------- fused split-K=2 bf16 reduce (+resid) + LayerNorm ----------------
__global__ __launch_bounds__(256) void sk2_ln(const unsigned short* __restrict__ p,
                                              const float* __restrict__ resid,
                                              const float* __restrict__ g,
                                              const float* __restrict__ b,
                                              float* __restrict__ x2,
                                              unsigned short* __restrict__ xn) {
    __shared__ float sbuf[4];
    int row = blockIdx.x;
    int t = threadIdx.x;
    const size_t seg = (size_t)NROWS * D_MODEL;
    size_t base = (size_t)row * D_MODEL + t * 4;
    ushort4 a = *(const ushort4*)(p + base);
    ushort4 bb = *(const ushort4*)(p + base + seg);
    float4 r = *(const float4*)(resid + base);
    float4 v;
    v.x = bf2f(a.x) + bf2f(bb.x) + r.x;
    v.y = bf2f(a.y) + bf2f(bb.y) + r.y;
    v.z = bf2f(a.z) + bf2f(bb.z) + r.z;
    v.w = bf2f(a.w) + bf2f(bb.w) + r.w;
    *(float4*)(x2 + base) = v;
    float s = v.x + v.y + v.z + v.w;
    for (int o = 32; o; o >>= 1) s += __shfl_down(s, o, 64);
    if ((t & 63) == 0) sbuf[t >> 6] = s;
    __syncthreads();
    float mu = (sbuf[0] + sbuf[1] + sbuf[2] + sbuf[3]) * (1.0f / D_MODEL);
    __syncthreads();
    float d0 = v.x - mu, d1 = v.y - mu, d2 = v.z - mu, d3 = v.w - mu;
    float qq = d0*d0 + d1*d1 + d2*d2 + d3*d3;
    for (int o = 32; o; o >>= 1) qq += __shfl_down(qq, o, 64);
    if ((t & 63) == 0) sbuf[t >> 6] = qq;
    __syncthreads();
    float var = (sbuf[0] + sbuf[1] + sbuf[2] + sbuf[3]) * (1.0f / D_MODEL);
    float rs = rsqrtf(var + 1e-5f);
    float4 gv = ((const float4*)g)[t];
    float4 bv = ((const float4*)b)[t];
    ushort4 st;
    st.x = f2bf(d0 * rs * gv.x + bv.x);
    st.y = f2bf(d1 * rs * gv.y + bv.y);
    st.z = f2bf(d2 * rs * gv.z + bv.z);
    st.w = f2bf(d3 * rs * gv.w + bv.w);
    ((ushort4*)(xn + (size_t)row * D_MODEL))[t] = st;
}

// ---------------- split-K=2 bf16 reduce + bias + resid (final output) ----------------
__global__ __launch_bounds__(256) void sk2_reduce(const unsigned short* __restrict__ p,
                                                  const float* __restrict__ bias,
                                                  const float* __restrict__ resid,
                                                  float* __restrict__ o) {
    int i = (blockIdx.x * 256 + threadIdx.x) * 4;
    const size_t seg = (size_t)NROWS * D_MODEL;
    ushort4 a = *(const ushort4*)(p + i);
    ushort4 b = *(const ushort4*)(p + i + seg);
    float4 r = *(const float4*)(resid + i);
    float4 bb = *(const float4*)(bias + (i & (D_MODEL - 1)));
    float4 o4;
    o4.x = bf2f(a.x) + bf2f(b.x) + r.x + bb.x;
    o4.y = bf2f(a.y) + bf2f(b.y) + r.y + bb.y;
    o4.z = bf2f(a.z) + bf2f(b.z) + r.z + bb.z;
    o4.w = bf2f(a.w) + bf2f(b.w) + r.w + bb.w;
    *(float4*)(o + i) = o4;
}

// ---------------- fused conv+SiLU+x_proj GEMM (no u materialization) ----------------
__global__ __launch_bounds__(256) void xproj_conv_gemm(
    const unsigned short* __restrict__ xz, const float* __restrict__ cw,
    const float* __restrict__ cb,
    const unsigned short* __restrict__ B,   // w_xp [128][1536]
    unsigned short* __restrict__ xq) {
    __shared__ unsigned short As[128 * 32];
    __shared__ unsigned short Bs[128 * 32];
    int t = threadIdx.x, l = t & 63, w = t >> 6;
    int m0 = blockIdx.x * 128;
    int kbase = blockIdx.y * 384;
    int c0 = 2 * w, c1 = 2 * w + 1;
    int srow = l >> 2, scol = (l & 3) * 8;
    const unsigned short* Bg0 = B + (size_t)(16 * c0 + srow) * D_INNER + kbase + scol;
    const unsigned short* Bg1 = B + (size_t)(16 * c1 + srow) * D_INNER + kbase + scol;
    int wr = w >> 1, wc = w & 1;
    int aoff = (wr * 64 + (l & 15)) * 32 + (l >> 4) * 8;
    int boff = (wc * 64 + (l & 15)) * 32 + (l >> 4) * 8;

    f32x4 acc[4][4] = {};

    for (int ti = 0; ti < 12; ti++) {
        int k0 = ti * 32;
        gload16(Bg0 + k0, &Bs[c0 * 512]);
        gload16(Bg1 + k0, &Bs[c1 * 512]);
        #pragma unroll
        for (int cc = 0; cc < 2; cc++) {
            int ch = 2 * w + cc;
            int bl = m0 + 16 * ch + srow;
            int d0 = kbase + k0 + scol;
            int lq = bl & (SEQ - 1);
            u16x8 rr[4];
            #pragma unroll
            for (int kk = 0; kk < 4; kk++) {
                if (lq - 3 + kk >= 0)
                    rr[kk] = *(const u16x8*)(xz + (size_t)(bl - 3 + kk) * (2 * D_INNER) + d0);
                else
                    rr[kk] = (u16x8)0;
            }
            float4 cb0 = *(const float4*)(cb + d0);
            float4 cb1 = *(const float4*)(cb + d0 + 4);
            float av[8];
            av[0] = cb0.x; av[1] = cb0.y; av[2] = cb0.z; av[3] = cb0.w;
            av[4] = cb1.x; av[5] = cb1.y; av[6] = cb1.z; av[7] = cb1.w;
            u16x8 o;
            #pragma unroll
            for (int j = 0; j < 8; j++) {
                float4 wv = *(const float4*)(cw + (d0 + j) * 4);
                float s = av[j];
                s += bf2f((unsigned short)rr[0][j]) * wv.x;
                s += bf2f((unsigned short)rr[1][j]) * wv.y;
                s += bf2f((unsigned short)rr[2][j]) * wv.z;
                s += bf2f((unsigned short)rr[3][j]) * wv.w;
                o[j] = f2bf(silu_f(s));
            }
            *(u16x8*)(&As[ch * 512 + l * 8]) = o;
        }
        __syncthreads();
        bf16x8 af[4], bfv[4];
        #pragma unroll
        for (int i = 0; i < 4; i++) af[i] = *(const bf16x8*)(&As[aoff + i * 512]);
        #pragma unroll
        for (int i = 0; i < 4; i++) bfv[i] = *(const bf16x8*)(&Bs[boff + i * 512]);
        __builtin_amdgcn_s_setprio(1);
        #pragma unroll
        for (int mi = 0; mi < 4; mi++)
            #pragma unroll
            for (int ni = 0; ni < 4; ni++)
                acc[mi][ni] = __builtin_amdgcn_mfma_f32_16x16x32_bf16(af[mi], bfv[ni], acc[mi][ni], 0, 0, 0);
        __builtin_amdgcn_s_setprio(0);
        __syncthreads();
    }

    unsigned short* Cb = xq + blockIdx.y * 128;
    int colb = wc * 64 + (l & 15);
    int rowb = m0 + wr * 64 + (l >> 4) * 4;
    #pragma unroll
    for (int ni = 0; ni < 4; ni++) {
        int col = colb + ni * 16;
        #pragma unroll
        for (int mi = 0; mi < 4; mi++) {
            #pragma unroll
            for (int j = 0; j < 4; j++) {
                int row = rowb + mi * 16 + j;
                Cb[(size_t)row * XQW + col] = f2bf(acc[mi][ni][j]);
            }
        }
    }
}

// ---------------- fused dt_proj: A = sum_z xq[:, z*128+0..64], K=64, softplus ----------------
__global__ __launch_bounds__(256) void dt_fused(
    const unsigned short* __restrict__ xq,
    const unsigned short* __restrict__ wdt,   // [1536][64]
    const float* __restrict__ bias,
    unsigned short* __restrict__ dl) {        // [4096][1536]
    __shared__ unsigned short As[2][128 * 32];
    __shared__ unsigned short Bs[2][128 * 32];
    int t = threadIdx.x, l = t & 63, w = t >> 6;
    int nx = gridDim.x;
    int nwg = nx * gridDim.y;
    int bid = blockIdx.y * nx + blockIdx.x;
    int q = nwg >> 3;
    int swz = (bid & 7) * q + (bid >> 3);
    int m0 = (swz / nx) * 128, n0 = (swz % nx) * 128;
    int c0 = 2 * w, c1 = 2 * w + 1;
    int srow = l >> 2, scol = (l & 3) * 8;
    #pragma unroll
    for (int kc = 0; kc < 2; kc++) {
        gload16(wdt + (size_t)(n0 + 16 * c0 + srow) * 64 + kc * 32 + scol, &Bs[kc][c0 * 512]);
        gload16(wdt + (size_t)(n0 + 16 * c1 + srow) * 64 + kc * 32 + scol, &Bs[kc][c1 * 512]);
    }
    #pragma unroll
    for (int kc = 0; kc < 2; kc++) {
        #pragma unroll
        for (int cc = 0; cc < 2; cc++) {
            int ch = 2 * w + cc;
            int row = m0 + 16 * ch + srow;
            int col = kc * 32 + scol;
            const unsigned short* xr = xq + (size_t)row * XQW + col;
            u16x8 a0 = *(const u16x8*)(xr);
            u16x8 a1 = *(const u16x8*)(xr + 128);
            u16x8 a2 = *(const u16x8*)(xr + 256);
            u16x8 a3 = *(const u16x8*)(xr + 384);
            u16x8 o;
            #pragma unroll
            for (int j = 0; j < 8; j++)
                o[j] = f2bf(bf2f((unsigned short)a0[j]) + bf2f((unsigned short)a1[j]) +
                            bf2f((unsigned short)a2[j]) + bf2f((unsigned short)a3[j]));
            *(u16x8*)(&As[kc][ch * 512 + l * 8]) = o;
        }
    }
    __syncthreads();
    int wr = w >> 1, wc = w & 1;
    int aoff = (wr * 64 + (l & 15)) * 32 + (l >> 4) * 8;
    int boff = (wc * 64 + (l & 15)) * 32 + (l >> 4) * 8;
    f32x4 acc[4][4] = {};
    #pragma unroll
    for (int kc = 0; kc < 2; kc++) {
        bf16x8 af[4], bfv[4];
        #pragma unroll
        for (int i = 0; i < 4; i++) af[i] = *(const bf16x8*)(&As[kc][aoff + i * 512]);
        #pragma unroll
        for (int i = 0; i < 4; i++) bfv[i] = *(const bf16x8*)(&Bs[kc][boff + i * 512]);
        #pragma unroll
        for (int mi = 0; mi < 4; mi++)
            #pragma unroll
            for (int ni = 0; ni < 4; ni++)
                acc[mi][ni] = __builtin_amdgcn_mfma_f32_16x16x32_bf16(af[mi], bfv[ni], acc[mi][ni], 0, 0, 0);
    }
    int colb = n0 + wc * 64 + (l & 15);
    int rowb = m0 + wr * 64 + (l >> 4) * 4;
    #pragma unroll
    for (int ni = 0; ni < 4; ni++) {
        int col = colb + ni * 16;
        float bv = bias[col];
        #pragma unroll
        for (int mi = 0; mi < 4; mi++) {
            #pragma unroll
            for (int j = 0; j < 4; j++) {
                int row = rowb + mi * 16 + j;
                dl[(size_t)row * D_INNER + col] = f2bf(softplus_f(acc[mi][ni][j] + bv));
            }
        }
    }
}

// ---------------- selective scan: pass A (u recomputed from xz; bf16 P,S) ----------------
__global__ __launch_bounds__(256) void scan_passA(const unsigned short* __restrict__ delta,
                                                  const unsigned short* __restrict__ xz,
                                                  const float* __restrict__ cw,
                                                  const float* __restrict__ cb,
                                                  const unsigned short* __restrict__ xq,
                                                  const float* __restrict__ A_log,
                                                  unsigned short* __restrict__ P,
                                                  unsigned short* __restrict__ S) {
    int d = blockIdx.x * 256 + threadIdx.x;
    int c = blockIdx.y, b = blockIdx.z;
    __shared__ float bc[LC][16];
    int base_row = b * SEQ + c * LC;
    for (int e = threadIdx.x; e < LC * 16; e += 256) {
        int lrr = e >> 4, col = e & 15;
        const unsigned short* xr = xq + (size_t)(base_row + lrr) * XQW + 64 + col;
        bc[lrr][col] = bf2f(xr[0]) + bf2f(xr[128]) + bf2f(xr[256]) + bf2f(xr[384]);
    }
    __syncthreads();
    float Ad[8];
    #pragma unroll
    for (int n = 0; n < 8; n++) Ad[n] = -__expf(A_log[d * 8 + n]);
    float4 wv = *(const float4*)(cw + d * 4);
    float cbv = cb[d];
    // conv window: w0=x[bl-3], w1=x[bl-2], w2=x[bl-1]; zeros at sequence start (c==0)
    float w0 = 0.0f, w1 = 0.0f, w2 = 0.0f;
    if (c != 0) {
        w0 = bf2f(xz[(size_t)(base_row - 3) * (2 * D_INNER) + d]);
        w1 = bf2f(xz[(size_t)(base_row - 2) * (2 * D_INNER) + d]);
        w2 = bf2f(xz[(size_t)(base_row - 1) * (2 * D_INNER) + d]);
    }
    float prod[8], hs[8];
    #pragma unroll
    for (int n = 0; n < 8; n++) { prod[n] = 1.0f; hs[n] = 0.0f; }
    for (int lrr = 0; lrr < LC; lrr++) {
        int row = base_row + lrr;
        float w3 = bf2f(xz[(size_t)row * (2 * D_INNER) + d]);
        float uu = silu_f(cbv + w0 * wv.x + w1 * wv.y + w2 * wv.z + w3 * wv.w);
        w0 = w1; w1 = w2; w2 = w3;
        float dl = bf2f(delta[(size_t)row * D_INNER + d]);
        float du = dl * uu;
        #pragma unroll
        for (int n = 0; n < 8; n++) {
            float dA = __expf(dl * Ad[n]);
            prod[n] *= dA;
            hs[n] = dA * hs[n] + du * bc[lrr][n];
        }
    }
    size_t o = ((size_t)((size_t)b * NC + c) * D_INNER + d) * 8;
    u16x8 po, so;
    #pragma unroll
    for (int n = 0; n < 8; n++) { po[n] = f2bf(prod[n]); so[n] = f2bf(hs[n]); }
    *(u16x8*)(P + o) = po;
    *(u16x8*)(S + o) = so;
}

// ---------------- scan: pass B (bf16 in, bf16 hstart out; f32 accumulate) ----------------
__global__ __launch_bounds__(256) void scan_passB(const unsigned short* __restrict__ P,
                                                  const unsigned short* __restrict__ S,
                                                  unsigned short* __restrict__ hstart) {
    int tid = blockIdx.x * 256 + threadIdx.x;
    int b = tid / (D_INNER * 8);
    int rem = tid % (D_INNER * 8);
    float h = 0.0f;
    for (int c = 0; c < NC; c++) {
        size_t o = (size_t)(b * NC + c) * (D_INNER * 8) + rem;
        hstart[o] = f2bf(h);
        h = bf2f(P[o]) * h + bf2f(S[o]);
    }
}

// ---------------- scan: pass C -> bf16 ygate (u recomputed; bf16 hstart in) ----------------
__global__ __launch_bounds__(256) void scan_passC(const unsigned short* __restrict__ delta,
                                                  const unsigned short* __restrict__ xz,
                                                  const float* __restrict__ cw,
                                                  const float* __restrict__ cb,
                                                  const unsigned short* __restrict__ xq,
                                                  const float* __restrict__ A_log,
                                                  const unsigned short* __restrict__ hstart,
                                                  const float* __restrict__ Dp,
                                                  unsigned short* __restrict__ ygate) {
    int d = blockIdx.x * 256 + threadIdx.x;
    int c = blockIdx.y, b = blockIdx.z;
    __shared__ float bc[LC][16];
    int base_row = b * SEQ + c * LC;
    for (int e = threadIdx.x; e < LC * 16; e += 256) {
        int lrr = e >> 4, col = e & 15;
        const unsigned short* xr = xq + (size_t)(base_row + lrr) * XQW + 64 + col;
        bc[lrr][col] = bf2f(xr[0]) + bf2f(xr[128]) + bf2f(xr[256]) + bf2f(xr[384]);
    }
    __syncthreads();
    float Ad[8];
    #pragma unroll
    for (int n = 0; n < 8; n++) Ad[n] = -__expf(A_log[d * 8 + n]);
    float4 wv = *(const float4*)(cw + d * 4);
    float cbv = cb[d];
    float w0 = 0.0f, w1 = 0.0f, w2 = 0.0f;
    if (c != 0) {
        w0 = bf2f(xz[(size_t)(base_row - 3) * (2 * D_INNER) + d]);
        w1 = bf2f(xz[(size_t)(base_row - 2) * (2 * D_INNER) + d]);
        w2 = bf2f(xz[(size_t)(base_row - 1) * (2 * D_INNER) + d]);
    }
    float h[8];
    size_t ho = ((size_t)((size_t)b * NC + c) * D_INNER + d) * 8;
    u16x8 hv = *(const u16x8*)(hstart + ho);
    #pragma unroll
    for (int n = 0; n < 8; n++) h[n] = bf2f((unsigned short)hv[n]);
    float Dd = Dp[d];
    for (int lrr = 0; lrr < LC; lrr++) {
        int row = base_row + lrr;
        float w3 = bf2f(xz[(size_t)row * (2 * D_INNER) + d]);
        float uu = silu_f(cbv + w0 * wv.x + w1 * wv.y + w2 * wv.z + w3 * wv.w);
        w0 = w1; w1 = w2; w2 = w3;
        float dl = bf2f(delta[(size_t)row * D_INNER + d]);
        float du = dl * uu;
        float y = 0.0f;
        #pragma unroll
        for (int n = 0; n < 8; n++) {
            float dA = __expf(dl * Ad[n]);
            h[n] = dA * h[n] + du * bc[lrr][n];
            y += h[n] * bc[lrr][8 + n];
        }
        y += uu * Dd;
        float z = bf2f(xz[(size_t)row * (2 * D_INNER) + D_INNER + d]);
        ygate[(size_t)row * D_INNER + d] = f2bf(y * silu_f(z));
    }
}

// ---------------- launch ----------------
extern "C" void kernel_launch(void* const* d_in, const int* in_sizes, int n_in,
                              void* d_out, int out_size, void* d_ws, size_t ws_size,
                              hipStream_t stream) {
    const float* x         = (const float*)d_in[0];
    const float* ln1_g     = (const float*)d_in[1];
    const float* ln1_b     = (const float*)d_in[2];
    const float* ln2_g     = (const float*)d_in[3];
    const float* ln2_b     = (const float*)d_in[4];
    const float* in_proj_w = (const float*)d_in[5];
    const float* conv_w    = (const float*)d_in[6];
    const float* conv_b    = (const float*)d_in[7];
    const float* x_proj_w  = (const float*)d_in[8];
    const float* dt_proj_w = (const float*)d_in[9];
    const float* dt_proj_b = (const float*)d_in[10];
    const float* A_log     = (const float*)d_in[11];
    const float* Dp        = (const float*)d_in[12];
    const float* out_proj_w= (const float*)d_in[13];
    const float* ffn_w1    = (const float*)d_in[14];
    const float* ffn_b1    = (const float*)d_in[15];
    const float* ffn_w2    = (const float*)d_in[16];
    const float* ffn_b2    = (const float*)d_in[17];
    float* out = (float*)d_out;

    // ---- workspace layout ----
    const size_t SCN = (size_t)BATCH * NC * D_INNER * 8;    // 786432 elements
    unsigned short* P   = (unsigned short*)d_ws;            // bf16 scan state
    unsigned short* S   = P + SCN;
    unsigned short* hst = S + SCN;
    float* x2    = (float*)(hst + SCN + SCN);               // 4096*1024 f32
    unsigned short* psum_bf = (unsigned short*)(x2 + (size_t)NROWS * D_MODEL);     // 2*4096*1024 bf16
    unsigned short* xq      = psum_bf + 2 * (size_t)NROWS * D_MODEL;               // 4096*512 bf16
    unsigned short* xz_bf   = xq + (size_t)NROWS * XQW;              // 4096*3072
    unsigned short* xp_bf   = xz_bf + (size_t)NROWS * 2 * D_INNER;   // 4096*1024 (reused as xn_bf)
    unsigned short* yg_bf   = xp_bf + (size_t)NROWS * D_MODEL;       // 4096*1536
    unsigned short* dl_bf   = yg_bf + (size_t)NROWS * D_INNER;       // 4096*1536
    unsigned short* w_in    = dl_bf + (size_t)NROWS * D_INNER;       // 3072*1024
    unsigned short* w_xp    = w_in + (size_t)2 * D_INNER * D_MODEL;  // 128*1536
    unsigned short* w_dt    = w_xp + (size_t)128 * D_INNER;          // 1536*64
    unsigned short* w_out   = w_dt + (size_t)D_INNER * DT_RANK;      // 1024*1536
    unsigned short* w_f1    = w_out + (size_t)D_MODEL * D_INNER;     // 2048*1024
    unsigned short* w_f2    = w_f1 + (size_t)D_FF * D_MODEL;         // 1024*2048
    unsigned short* hff_bf  = xz_bf;   // overlay: xz dead after scan_passC

    // 1. prep: weight conversions + x_proj pad + LN1
    prep_kernel<<<4528 + NROWS, 256, 0, stream>>>(
        in_proj_w, w_in, dt_proj_w, w_dt, out_proj_w, w_out, ffn_w1, w_f1, ffn_w2, w_f2,
        x_proj_w, w_xp, x, ln1_g, ln1_b, xp_bf);
    // 2. in_proj (4096 x 3072, K=1024) -> bf16   [8-phase 256x256]
    gemm8p<4, EPI_BF16, 1, 8><<<dim3(3072 / 256, NROWS / 256), 512, 0, stream>>>(
        xp_bf, D_MODEL, w_in, D_MODEL, D_MODEL, nullptr, xz_bf, 2 * D_INNER, nullptr, nullptr, 0);
    // 3. fused conv+silu+x_proj: xq bf16 partials (4096 x 4x128); u not materialized
    xproj_conv_gemm<<<dim3(NROWS / 128, 4), 256, 0, stream>>>(
        xz_bf, conv_w, conv_b, w_xp, xq);
    // 4. fused dt_proj + softplus (A = 4-way xq sum, K=64) -> delta bf16
    dt_fused<<<dim3(D_INNER / 128, NROWS / 128), 256, 0, stream>>>(
        xq, w_dt, dt_proj_b, dl_bf);
    // 5-7. selective scan (bf16 state; u recomputed from xz in A and C)
    scan_passA<<<dim3(D_INNER / 256, NC, BATCH), 256, 0, stream>>>(
        dl_bf, xz_bf, conv_w, conv_b, xq, A_log, P, S);
    scan_passB<<<(BATCH * D_INNER * 8) / 256, 256, 0, stream>>>(P, S, hst);
    scan_passC<<<dim3(D_INNER / 256, NC, BATCH), 256, 0, stream>>>(
        dl_bf, xz_bf, conv_w, conv_b, xq, A_log, hst, Dp, yg_bf);
    // 8. out_proj split-K=2 (K=768 each) -> bf16 partials  [4-phase 256x128]
    gemm8p<2, EPI_PBF16, 2, 4><<<dim3(D_MODEL / 128, NROWS / 256, 2), 512, 0, stream>>>(
        yg_bf, D_INNER, w_out, D_INNER, D_INNER / 2, nullptr, psum_bf, D_MODEL, nullptr, nullptr, 0);
    // 9. fused bf16 reduce + residual + LN2 -> x2 f32, xn bf16
    sk2_ln<<<NROWS, 256, 0, stream>>>(psum_bf, x, ln2_g, ln2_b, x2, xp_bf);
    // 10. ffn1 + gelu -> bf16 hff  (K=1024)  [4-phase 256x128]
    gemm8p<2, EPI_GELU_BF16, 1, 4><<<dim3(D_FF / 128, NROWS / 256), 512, 0, stream>>>(
        xp_bf, D_MODEL, w_f1, D_MODEL, D_MODEL, nullptr, hff_bf, D_FF, ffn_b1, nullptr, 0);
    // 11. ffn2 split-K=2 (K=1024 each) -> bf16 partials  [4-phase 256x128]
    gemm8p<2, EPI_PBF16, 2, 4><<<dim3(D_MODEL / 128, NROWS / 256, 2), 512, 0, stream>>>(
        hff_bf, D_FF, w_f2, D_FF, D_FF / 2, nullptr, psum_bf, D_MODEL, nullptr, nullptr, 0);
    // 12. final bf16 reduce + bias + residual -> out
    sk2_reduce<<<(NROWS * D_MODEL) / 1024, 256, 0, stream>>>(psum_bf, ffn_b2, x2, out);
}

// Round 18
// 263.328 us; speedup vs baseline: 1.0724x; 1.0724x over previous
//
#include <hip/hip_runtime.h>
#include <math.h>

#define D_MODEL 1024
#define D_STATE 8
#define D_CONV  4
#define D_INNER 1536
#define DT_RANK 64
#define D_FF    2048
#define BATCH   2
#define SEQ     2048
#define NROWS   (BATCH*SEQ)      // 4096
#define NC      32               // scan chunks
#define LC      (SEQ/NC)         // 64
#define XQW     512              // interleaved x_dbl partial width (4 x 128)

typedef short bf16x8 __attribute__((ext_vector_type(8)));
typedef unsigned short u16x8 __attribute__((ext_vector_type(8)));
typedef float f32x4  __attribute__((ext_vector_type(4)));

__device__ inline unsigned short f2bf(float x) {
    union { float f; unsigned u; } v; v.f = x;
    unsigned r = v.u + 0x7fffu + ((v.u >> 16) & 1u);
    return (unsigned short)(r >> 16);
}
__device__ inline float bf2f(unsigned short h) {
    union { unsigned u; float f; } v; v.u = ((unsigned)h) << 16;
    return v.f;
}
__device__ inline float softplus_f(float x) {
    return (x > 20.0f) ? x : log1pf(__expf(x));
}
__device__ inline float gelu_f(float x) {
    return 0.5f * x * (1.0f + erff(x * 0.70710678118654752f));
}
__device__ inline float silu_f(float x) {
    return x / (1.0f + __expf(-x));
}
__device__ inline void gload16(const unsigned short* g, unsigned short* l) {
    typedef unsigned int u32;
    __builtin_amdgcn_global_load_lds(
        (const __attribute__((address_space(1))) u32*)g,
        (__attribute__((address_space(3))) u32*)l, 16, 0, 0);
}

#define PHASE_SYNC_PRE()  do { __builtin_amdgcn_s_barrier(); \
                               asm volatile("s_waitcnt lgkmcnt(0)" ::: "memory"); } while (0)
#define PHASE_SYNC_POST() do { __builtin_amdgcn_s_barrier(); } while (0)

// ---------------- prep: weight conversions + xproj pad + LN1 ----------------
__global__ __launch_bounds__(256) void prep_kernel(
    const float* __restrict__ s0, unsigned short* __restrict__ d0,
    const float* __restrict__ s1, unsigned short* __restrict__ d1,
    const float* __restrict__ s2, unsigned short* __restrict__ d2,
    const float* __restrict__ s3, unsigned short* __restrict__ d3,
    const float* __restrict__ s4, unsigned short* __restrict__ d4,
    const float* __restrict__ xpw, unsigned short* __restrict__ xpd,
    const float* __restrict__ x, const float* __restrict__ g1,
    const float* __restrict__ b1, unsigned short* __restrict__ xout) {
    int b = blockIdx.x;
    if (b < 4400) {
        const float* s; unsigned short* d; int base;
        if      (b < 1536) { s = s0; d = d0; base = b * 2048; }
        else if (b < 1584) { s = s1; d = d1; base = (b - 1536) * 2048; }
        else if (b < 2352) { s = s2; d = d2; base = (b - 1584) * 2048; }
        else if (b < 3376) { s = s3; d = d3; base = (b - 2352) * 2048; }
        else               { s = s4; d = d4; base = (b - 3376) * 2048; }
        int i = base + threadIdx.x * 8;
        float4 v0 = *(const float4*)(s + i);
        float4 v1 = *(const float4*)(s + i + 4);
        ushort4 a, c;
        a.x = f2bf(v0.x); a.y = f2bf(v0.y); a.z = f2bf(v0.z); a.w = f2bf(v0.w);
        c.x = f2bf(v1.x); c.y = f2bf(v1.y); c.z = f2bf(v1.z); c.w = f2bf(v1.w);
        *(ushort4*)(d + i)     = a;
        *(ushort4*)(d + i + 4) = c;
    } else if (b < 4528) {
        int row = b - 4400;
        for (int c = threadIdx.x; c < D_INNER; c += 256)
            xpd[row * D_INNER + c] = (row < 80) ? f2bf(xpw[row * D_INNER + c]) : (unsigned short)0;
    } else {
        __shared__ float sbuf[4];
        int row = b - 4528;
        int t = threadIdx.x;
        float4 v = ((const float4*)(x + (size_t)row * D_MODEL))[t];
        float s = v.x + v.y + v.z + v.w;
        for (int o = 32; o; o >>= 1) s += __shfl_down(s, o, 64);
        if ((t & 63) == 0) sbuf[t >> 6] = s;
        __syncthreads();
        float mu = (sbuf[0] + sbuf[1] + sbuf[2] + sbuf[3]) * (1.0f / D_MODEL);
        __syncthreads();
        float e0 = v.x - mu, e1 = v.y - mu, e2 = v.z - mu, e3 = v.w - mu;
        float q = e0*e0 + e1*e1 + e2*e2 + e3*e3;
        for (int o = 32; o; o >>= 1) q += __shfl_down(q, o, 64);
        if ((t & 63) == 0) sbuf[t >> 6] = q;
        __syncthreads();
        float var = (sbuf[0] + sbuf[1] + sbuf[2] + sbuf[3]) * (1.0f / D_MODEL);
        float rs = rsqrtf(var + 1e-5f);
        float4 gv = ((const float4*)g1)[t];
        float4 bv = ((const float4*)b1)[t];
        ushort4 st;
        st.x = f2bf(e0 * rs * gv.x + bv.x);
        st.y = f2bf(e1 * rs * gv.y + bv.y);
        st.z = f2bf(e2 * rs * gv.z + bv.z);
        st.w = f2bf(e3 * rs * gv.w + bv.w);
        ((ushort4*)(xout + (size_t)row * D_MODEL))[t] = st;
    }
}

// ---------------- epilogue IDs ----------------
#define EPI_F32        0
#define EPI_GELU_BF16  4
#define EPI_BF16       6
#define EPI_SOFTPLUS_BF16 7
#define EPI_PBF16      9

// ================= 256-row MFMA GEMM (NT), PH=8 or PH=4 =================
template<int WN, int EPI, int SPLITK, int PH>
__global__ __launch_bounds__(512, 2) void gemm8p(
    const unsigned short* __restrict__ A, int lda,
    const unsigned short* __restrict__ Bm, int ldb, int K,
    float* __restrict__ Cf, unsigned short* __restrict__ Cb, int ldc,
    const float* __restrict__ bias,
    const float* __restrict__ resid, int ldr) {
    constexpr int WM = 8 / WN;
    constexpr int BN = WN * 64;
    constexpr int RW = 256 / WM;
    constexpr int CW = 64;
    constexpr int MI = RW / 16;
    constexpr int NI = CW / 16;
    constexpr int MIH = MI / 2, NIH = NI / 2;
    constexpr int ABYTES = 256 * 128;
    constexpr int BBYTES = BN * 128;
    constexpr int BOFF = 2 * ABYTES;
    __shared__ unsigned short lds[(2 * ABYTES + 2 * BBYTES) / 2];

    const int t = threadIdx.x, l = t & 63, w = t >> 6;
    const int wr = w / WN, wc = w % WN;

    const int nx = gridDim.x;
    const int nwg = nx * gridDim.y;
    int bid = blockIdx.y * nx + blockIdx.x;
    int q = nwg >> 3;
    int swz = (bid & 7) * q + (bid >> 3);
    const int m0 = (swz / nx) * 256, n0 = (swz % nx) * BN;
    const int kbase = (SPLITK > 1) ? blockIdx.z * K : 0;

    const int sr = l >> 3;
    const int sj = ((l & 7) * 16) ^ ((l >> 3) << 4);
    const int row_l = w * 8;
    const int row_c = (w >> 2) * 64 + (w & 3) * 8;

    auto STG = [&](int bufbyte, int rowbase, const unsigned short* G, int ldg, int gbase, int kt) {
        unsigned short* dst = (unsigned short*)((char*)lds + bufbyte + rowbase * 128);
        const unsigned short* src = G + (size_t)(gbase + rowbase + sr) * ldg + kbase + kt * 64 + (sj >> 1);
        gload16(src, dst);
    };
    auto S_Ah0 = [&](int b, int kt) {
        if (WN == 4) { STG(b * ABYTES, row_l, A, lda, m0, kt);       STG(b * ABYTES, 128 + row_l, A, lda, m0, kt); }
        else         { STG(b * ABYTES, row_c, A, lda, m0, kt);       STG(b * ABYTES, 128 + row_c, A, lda, m0, kt); }
    };
    auto S_Ah1 = [&](int b, int kt) {
        if (WN == 4) { STG(b * ABYTES, 64 + row_l, A, lda, m0, kt);  STG(b * ABYTES, 192 + row_l, A, lda, m0, kt); }
        else         { STG(b * ABYTES, 32 + row_c, A, lda, m0, kt);  STG(b * ABYTES, 160 + row_c, A, lda, m0, kt); }
    };
    auto S_Bc0 = [&](int b, int kt) {
        if (WN == 4) { STG(BOFF + b * BBYTES, row_c, Bm, ldb, n0, kt); STG(BOFF + b * BBYTES, 128 + row_c, Bm, ldb, n0, kt); }
        else         { STG(BOFF + b * BBYTES, row_c, Bm, ldb, n0, kt); }
    };
    auto S_Bc1 = [&](int b, int kt) {
        if (WN == 4) { STG(BOFF + b * BBYTES, 32 + row_c, Bm, ldb, n0, kt); STG(BOFF + b * BBYTES, 160 + row_c, Bm, ldb, n0, kt); }
        else         { STG(BOFF + b * BBYTES, 32 + row_c, Bm, ldb, n0, kt); }
    };

    auto LD = [&](int bytebase, int row, int kb) -> bf16x8 {
        int o = bytebase + row * 128 + (kb ^ ((row & 7) << 4));
        return *(const bf16x8*)((const char*)lds + o);
    };

    f32x4 acc[MI][NI] = {};
    bf16x8 af[MIH][2], b0v[NIH][2], b1v[NIH][2];

    auto LDA_set = [&](int buf, int qr, auto& dst) {
        #pragma unroll
        for (int mi = 0; mi < MIH; mi++)
            #pragma unroll
            for (int ks = 0; ks < 2; ks++)
                dst[mi][ks] = LD(buf * ABYTES, wr * RW + qr * (RW / 2) + mi * 16 + (l & 15),
                                 ks * 64 + (l >> 4) * 16);
    };
    auto LDB_set = [&](int buf, int qc, auto& dst) {
        #pragma unroll
        for (int ni2 = 0; ni2 < NIH; ni2++)
            #pragma unroll
            for (int ks = 0; ks < 2; ks++)
                dst[ni2][ks] = LD(BOFF + buf * BBYTES, wc * CW + qc * 32 + ni2 * 16 + (l & 15),
                                  ks * 64 + (l >> 4) * 16);
    };
    auto MFMA_Q = [&](int qr, int qc, auto& a_, auto& b_) {
        __builtin_amdgcn_s_setprio(1);
        #pragma unroll
        for (int mi = 0; mi < MIH; mi++)
            #pragma unroll
            for (int ni2 = 0; ni2 < NIH; ni2++)
                #pragma unroll
                for (int ks = 0; ks < 2; ks++)
                    acc[qr * MIH + mi][qc * NIH + ni2] =
                        __builtin_amdgcn_mfma_f32_16x16x32_bf16(a_[mi][ks], b_[ni2][ks],
                                                                acc[qr * MIH + mi][qc * NIH + ni2], 0, 0, 0);
        __builtin_amdgcn_s_setprio(0);
    };
    auto VMW8 = [&](bool last) {
        if (last)            asm volatile("s_waitcnt vmcnt(0)" ::: "memory");
        else if (WN == 4)    asm volatile("s_waitcnt vmcnt(6)" ::: "memory");
        else                 asm volatile("s_waitcnt vmcnt(5)" ::: "memory");
    };
    auto VMW4 = [&](bool last) {
        if (last)            asm volatile("s_waitcnt vmcnt(0)" ::: "memory");
        else if (WN == 4)    asm volatile("s_waitcnt vmcnt(4)" ::: "memory");
        else                 asm volatile("s_waitcnt vmcnt(3)" ::: "memory");
    };

    const int ni_ = K >> 7;

    S_Ah0(0, 0); S_Ah1(0, 0); S_Bc0(0, 0); S_Bc1(0, 0);
    S_Ah0(1, 1); S_Ah1(1, 1); S_Bc0(1, 1); S_Bc1(1, 1);
    if (WN == 4) asm volatile("s_waitcnt vmcnt(8)" ::: "memory");
    else         asm volatile("s_waitcnt vmcnt(6)" ::: "memory");
    __builtin_amdgcn_s_barrier();

    if constexpr (PH == 8) {
        for (int i = 0; i < ni_; i++) {
            const bool last = (i == ni_ - 1);
            const int t2 = 2 * i + 2, t3 = 2 * i + 3;
            LDA_set(0, 0, af); LDB_set(0, 0, b0v);
            if (i) S_Bc0(1, 2 * i + 1);
            PHASE_SYNC_PRE(); MFMA_Q(0, 0, af, b0v); PHASE_SYNC_POST();
            LDB_set(0, 1, b1v);
            if (!last) S_Ah0(0, t2);
            PHASE_SYNC_PRE(); MFMA_Q(0, 1, af, b1v); PHASE_SYNC_POST();
            LDA_set(0, 1, af);
            PHASE_SYNC_PRE(); MFMA_Q(1, 1, af, b1v); PHASE_SYNC_POST();
            LDB_set(0, 0, b0v);
            if (!last) { S_Ah1(0, t2); S_Bc1(0, t2); }
            VMW8(last);
            PHASE_SYNC_PRE(); MFMA_Q(1, 0, af, b0v); PHASE_SYNC_POST();
            LDA_set(1, 0, af); LDB_set(1, 0, b0v);
            if (!last) S_Bc0(0, t2);
            PHASE_SYNC_PRE(); MFMA_Q(0, 0, af, b0v); PHASE_SYNC_POST();
            LDB_set(1, 1, b1v);
            if (!last) S_Ah0(1, t3);
            PHASE_SYNC_PRE(); MFMA_Q(0, 1, af, b1v); PHASE_SYNC_POST();
            LDA_set(1, 1, af);
            PHASE_SYNC_PRE(); MFMA_Q(1, 1, af, b1v); PHASE_SYNC_POST();
            LDB_set(1, 0, b0v);
            if (!last) { S_Ah1(1, t3); S_Bc1(1, t3); }
            VMW8(last);
            PHASE_SYNC_PRE(); MFMA_Q(1, 0, af, b0v); PHASE_SYNC_POST();
        }
    } else {
        for (int i = 0; i < ni_; i++) {
            const bool last = (i == ni_ - 1);
            const int t2 = 2 * i + 2, t3 = 2 * i + 3;
            LDA_set(0, 0, af); LDB_set(0, 0, b0v); LDB_set(0, 1, b1v);
            if (i) { S_Bc0(1, 2 * i + 1); S_Ah1(1, 2 * i + 1); }
            PHASE_SYNC_PRE();
            MFMA_Q(0, 0, af, b0v); MFMA_Q(0, 1, af, b1v);
            PHASE_SYNC_POST();
            LDA_set(0, 1, af);
            if (!last) { S_Ah0(0, t2); S_Bc1(0, t2); }
            VMW4(last);
            PHASE_SYNC_PRE();
            MFMA_Q(1, 1, af, b1v); MFMA_Q(1, 0, af, b0v);
            PHASE_SYNC_POST();
            LDA_set(1, 0, af); LDB_set(1, 0, b0v); LDB_set(1, 1, b1v);
            if (!last) { S_Bc0(0, t2); S_Ah1(0, t2); }
            PHASE_SYNC_PRE();
            MFMA_Q(0, 0, af, b0v); MFMA_Q(0, 1, af, b1v);
            PHASE_SYNC_POST();
            LDA_set(1, 1, af);
            if (!last) { S_Ah0(1, t3); S_Bc1(1, t3); }
            VMW4(last);
            PHASE_SYNC_PRE();
            MFMA_Q(1, 1, af, b1v); MFMA_Q(1, 0, af, b0v);
            PHASE_SYNC_POST();
        }
    }

    float* Cfp = Cf;
    unsigned short* Cbp = Cb;
    if (SPLITK > 1) {
        Cfp += (size_t)blockIdx.z * NROWS * ldc;
        Cbp += (size_t)blockIdx.z * NROWS * ldc;
    }
    #pragma unroll
    for (int ni2 = 0; ni2 < NI; ni2++) {
        int col = n0 + wc * CW + ni2 * 16 + (l & 15);
        float bv = 0.0f;
        if (EPI == EPI_GELU_BF16) bv = bias[col];
        #pragma unroll
        for (int mi = 0; mi < MI; mi++) {
            #pragma unroll
            for (int j = 0; j < 4; j++) {
                int row = m0 + wr * RW + mi * 16 + (l >> 4) * 4 + j;
                float v = acc[mi][ni2][j];
                if (EPI == EPI_GELU_BF16)  v = gelu_f(v + bv);
                if (EPI == EPI_GELU_BF16 || EPI == EPI_BF16 || EPI == EPI_PBF16) {
                    Cbp[(size_t)row * ldc + col] = f2bf(v);
                } else {
                    Cfp[(size_t)row * ldc + col] = v;
                }
            }
        }
    }
}

// ---------------- fused split-K=2 bf16 reduce (+resid) + LayerNorm ----------------
__global__ __launch_bounds__(256) void sk2_ln(const unsigned short* __restrict__ p,
                                              const float* __restrict__ resid,
                                              const float* __restrict__ g,
                                              const float* __restrict__ b,
                                              float* __restrict__ x2,
                                              unsigned short* __restrict__ xn) {
    __shared__ float sbuf[4];
    int row = blockIdx.x;
    int t = threadIdx.x;
    const size_t seg = (size_t)NROWS * D_MODEL;
    size_t base = (size_t)row * D_MODEL + t * 4;
    ushort4 a = *(const ushort4*)(p + base);
    ushort4 bb = *(const ushort4*)(p + base + seg);
    float4 r = *(const float4*)(resid + base);
    float4 v;
    v.x = bf2f(a.x) + bf2f(bb.x) + r.x;
    v.y = bf2f(a.y) + bf2f(bb.y) + r.y;
    v.z = bf2f(a.z) + bf2f(bb.z) + r.z;
    v.w = bf2f(a.w) + bf2f(bb.w) + r.w;
    *(float4*)(x2 + base) = v;
    float s = v.x + v.y + v.z + v.w;
    for (int o = 32; o; o >>= 1) s += __shfl_down(s, o, 64);
    if ((t & 63) == 0) sbuf[t >> 6] = s;
    __syncthreads();
    float mu = (sbuf[0] + sbuf[1] + sbuf[2] + sbuf[3]) * (1.0f / D_MODEL);
    __syncthreads();
    float d0 = v.x - mu, d1 = v.y - mu, d2 = v.z - mu, d3 = v.w - mu;
    float qq = d0*d0 + d1*d1 + d2*d2 + d3*d3;
    for (int o = 32; o; o >>= 1) qq += __shfl_down(qq, o, 64);
    if ((t & 63) == 0) sbuf[t >> 6] = qq;
    __syncthreads();
    float var = (sbuf[0] + sbuf[1] + sbuf[2] + sbuf[3]) * (1.0f / D_MODEL);
    float rs = rsqrtf(var + 1e-5f);
    float4 gv = ((const float4*)g)[t];
    float4 bv = ((const float4*)b)[t];
    ushort4 st;
    st.x = f2bf(d0 * rs * gv.x + bv.x);
    st.y = f2bf(d1 * rs * gv.y + bv.y);
    st.z = f2bf(d2 * rs * gv.z + bv.z);
    st.w = f2bf(d3 * rs * gv.w + bv.w);
    ((ushort4*)(xn + (size_t)row * D_MODEL))[t] = st;
}

// ---------------- split-K=2 bf16 reduce + bias + resid (final output) ----------------
__global__ __launch_bounds__(256) void sk2_reduce(const unsigned short* __restrict__ p,
                                                  const float* __restrict__ bias,
                                                  const float* __restrict__ resid,
                                                  float* __restrict__ o) {
    int i = (blockIdx.x * 256 + threadIdx.x) * 4;
    const size_t seg = (size_t)NROWS * D_MODEL;
    ushort4 a = *(const ushort4*)(p + i);
    ushort4 b = *(const ushort4*)(p + i + seg);
    float4 r = *(const float4*)(resid + i);
    float4 bb = *(const float4*)(bias + (i & (D_MODEL - 1)));
    float4 o4;
    o4.x = bf2f(a.x) + bf2f(b.x) + r.x + bb.x;
    o4.y = bf2f(a.y) + bf2f(b.y) + r.y + bb.y;
    o4.z = bf2f(a.z) + bf2f(b.z) + r.z + bb.z;
    o4.w = bf2f(a.w) + bf2f(b.w) + r.w + bb.w;
    *(float4*)(o + i) = o4;
}

// ---------------- fused conv+SiLU+x_proj GEMM ----------------
__global__ __launch_bounds__(256) void xproj_conv_gemm(
    const unsigned short* __restrict__ xz, const float* __restrict__ cw,
    const float* __restrict__ cb, unsigned short* __restrict__ u,
    const unsigned short* __restrict__ B,   // w_xp [128][1536]
    unsigned short* __restrict__ xq) {
    __shared__ unsigned short As[128 * 32];
    __shared__ unsigned short Bs[128 * 32];
    int t = threadIdx.x, l = t & 63, w = t >> 6;
    int m0 = blockIdx.x * 128;
    int kbase = blockIdx.y * 384;
    int c0 = 2 * w, c1 = 2 * w + 1;
    int srow = l >> 2, scol = (l & 3) * 8;
    const unsigned short* Bg0 = B + (size_t)(16 * c0 + srow) * D_INNER + kbase + scol;
    const unsigned short* Bg1 = B + (size_t)(16 * c1 + srow) * D_INNER + kbase + scol;
    int wr = w >> 1, wc = w & 1;
    int aoff = (wr * 64 + (l & 15)) * 32 + (l >> 4) * 8;
    int boff = (wc * 64 + (l & 15)) * 32 + (l >> 4) * 8;

    f32x4 acc[4][4] = {};

    for (int ti = 0; ti < 12; ti++) {
        int k0 = ti * 32;
        gload16(Bg0 + k0, &Bs[c0 * 512]);
        gload16(Bg1 + k0, &Bs[c1 * 512]);
        #pragma unroll
        for (int cc = 0; cc < 2; cc++) {
            int ch = 2 * w + cc;
            int bl = m0 + 16 * ch + srow;
            int d0 = kbase + k0 + scol;
            int lq = bl & (SEQ - 1);
            u16x8 rr[4];
            #pragma unroll
            for (int kk = 0; kk < 4; kk++) {
                if (lq - 3 + kk >= 0)
                    rr[kk] = *(const u16x8*)(xz + (size_t)(bl - 3 + kk) * (2 * D_INNER) + d0);
                else
                    rr[kk] = (u16x8)0;
            }
            float4 cb0 = *(const float4*)(cb + d0);
            float4 cb1 = *(const float4*)(cb + d0 + 4);
            float av[8];
            av[0] = cb0.x; av[1] = cb0.y; av[2] = cb0.z; av[3] = cb0.w;
            av[4] = cb1.x; av[5] = cb1.y; av[6] = cb1.z; av[7] = cb1.w;
            u16x8 o;
            #pragma unroll
            for (int j = 0; j < 8; j++) {
                float4 wv = *(const float4*)(cw + (d0 + j) * 4);
                float s = av[j];
                s += bf2f((unsigned short)rr[0][j]) * wv.x;
                s += bf2f((unsigned short)rr[1][j]) * wv.y;
                s += bf2f((unsigned short)rr[2][j]) * wv.z;
                s += bf2f((unsigned short)rr[3][j]) * wv.w;
                o[j] = f2bf(silu_f(s));
            }
            *(u16x8*)(&As[ch * 512 + l * 8]) = o;
            *(u16x8*)(u + (size_t)bl * D_INNER + d0) = o;
        }
        __syncthreads();
        bf16x8 af[4], bfv[4];
        #pragma unroll
        for (int i = 0; i < 4; i++) af[i] = *(const bf16x8*)(&As[aoff + i * 512]);
        #pragma unroll
        for (int i = 0; i < 4; i++) bfv[i] = *(const bf16x8*)(&Bs[boff + i * 512]);
        __builtin_amdgcn_s_setprio(1);
        #pragma unroll
        for (int mi = 0; mi < 4; mi++)
            #pragma unroll
            for (int ni = 0; ni < 4; ni++)
                acc[mi][ni] = __builtin_amdgcn_mfma_f32_16x16x32_bf16(af[mi], bfv[ni], acc[mi][ni], 0, 0, 0);
        __builtin_amdgcn_s_setprio(0);
        __syncthreads();
    }

    unsigned short* Cb = xq + blockIdx.y * 128;
    int colb = wc * 64 + (l & 15);
    int rowb = m0 + wr * 64 + (l >> 4) * 4;
    #pragma unroll
    for (int ni = 0; ni < 4; ni++) {
        int col = colb + ni * 16;
        #pragma unroll
        for (int mi = 0; mi < 4; mi++) {
            #pragma unroll
            for (int j = 0; j < 4; j++) {
                int row = rowb + mi * 16 + j;
                Cb[(size_t)row * XQW + col] = f2bf(acc[mi][ni][j]);
            }
        }
    }
}

// ---------------- fused dt_proj: A = sum_z xq[:, z*128+0..64], K=64, softplus ----------------
__global__ __launch_bounds__(256) void dt_fused(
    const unsigned short* __restrict__ xq,
    const unsigned short* __restrict__ wdt,   // [1536][64]
    const float* __restrict__ bias,
    unsigned short* __restrict__ dl) {        // [4096][1536]
    __shared__ unsigned short As[2][128 * 32];
    __shared__ unsigned short Bs[2][128 * 32];
    int t = threadIdx.x, l = t & 63, w = t >> 6;
    int nx = gridDim.x;
    int nwg = nx * gridDim.y;
    int bid = blockIdx.y * nx + blockIdx.x;
    int q = nwg >> 3;
    int swz = (bid & 7) * q + (bid >> 3);
    int m0 = (swz / nx) * 128, n0 = (swz % nx) * 128;
    int c0 = 2 * w, c1 = 2 * w + 1;
    int srow = l >> 2, scol = (l & 3) * 8;
    #pragma unroll
    for (int kc = 0; kc < 2; kc++) {
        gload16(wdt + (size_t)(n0 + 16 * c0 + srow) * 64 + kc * 32 + scol, &Bs[kc][c0 * 512]);
        gload16(wdt + (size_t)(n0 + 16 * c1 + srow) * 64 + kc * 32 + scol, &Bs[kc][c1 * 512]);
    }
    #pragma unroll
    for (int kc = 0; kc < 2; kc++) {
        #pragma unroll
        for (int cc = 0; cc < 2; cc++) {
            int ch = 2 * w + cc;
            int row = m0 + 16 * ch + srow;
            int col = kc * 32 + scol;
            const unsigned short* xr = xq + (size_t)row * XQW + col;
            u16x8 a0 = *(const u16x8*)(xr);
            u16x8 a1 = *(const u16x8*)(xr + 128);
            u16x8 a2 = *(const u16x8*)(xr + 256);
            u16x8 a3 = *(const u16x8*)(xr + 384);
            u16x8 o;
            #pragma unroll
            for (int j = 0; j < 8; j++)
                o[j] = f2bf(bf2f((unsigned short)a0[j]) + bf2f((unsigned short)a1[j]) +
                            bf2f((unsigned short)a2[j]) + bf2f((unsigned short)a3[j]));
            *(u16x8*)(&As[kc][ch * 512 + l * 8]) = o;
        }
    }
    __syncthreads();
    int wr = w >> 1, wc = w & 1;
    int aoff = (wr * 64 + (l & 15)) * 32 + (l >> 4) * 8;
    int boff = (wc * 64 + (l & 15)) * 32 + (l >> 4) * 8;
    f32x4 acc[4][4] = {};
    #pragma unroll
    for (int kc = 0; kc < 2; kc++) {
        bf16x8 af[4], bfv[4];
        #pragma unroll
        for (int i = 0; i < 4; i++) af[i] = *(const bf16x8*)(&As[kc][aoff + i * 512]);
        #pragma unroll
        for (int i = 0; i < 4; i++) bfv[i] = *(const bf16x8*)(&Bs[kc][boff + i * 512]);
        #pragma unroll
        for (int mi = 0; mi < 4; mi++)
            #pragma unroll
            for (int ni = 0; ni < 4; ni++)
                acc[mi][ni] = __builtin_amdgcn_mfma_f32_16x16x32_bf16(af[mi], bfv[ni], acc[mi][ni], 0, 0, 0);
    }
    int colb = n0 + wc * 64 + (l & 15);
    int rowb = m0 + wr * 64 + (l >> 4) * 4;
    #pragma unroll
    for (int ni = 0; ni < 4; ni++) {
        int col = colb + ni * 16;
        float bv = bias[col];
        #pragma unroll
        for (int mi = 0; mi < 4; mi++) {
            #pragma unroll
            for (int j = 0; j < 4; j++) {
                int row = rowb + mi * 16 + j;
                dl[(size_t)row * D_INNER + col] = f2bf(softplus_f(acc[mi][ni][j] + bv));
            }
        }
    }
}

// ---------------- selective scan: pass A (bf16 P,S) ----------------
__global__ __launch_bounds__(256) void scan_passA(const unsigned short* __restrict__ delta,
                                                  const unsigned short* __restrict__ u,
                                                  const unsigned short* __restrict__ xq,
                                                  const float* __restrict__ A_log,
                                                  unsigned short* __restrict__ P,
                                                  unsigned short* __restrict__ S) {
    int d = blockIdx.x * 256 + threadIdx.x;
    int c = blockIdx.y, b = blockIdx.z;
    __shared__ float bc[LC][16];
    int base_row = b * SEQ + c * LC;
    for (int e = threadIdx.x; e < LC * 16; e += 256) {
        int lrr = e >> 4, col = e & 15;
        const unsigned short* xr = xq + (size_t)(base_row + lrr) * XQW + 64 + col;
        bc[lrr][col] = bf2f(xr[0]) + bf2f(xr[128]) + bf2f(xr[256]) + bf2f(xr[384]);
    }
    __syncthreads();
    float Ad[8];
    #pragma unroll
    for (int n = 0; n < 8; n++) Ad[n] = -__expf(A_log[d * 8 + n]);
    float prod[8], hs[8];
    #pragma unroll
    for (int n = 0; n < 8; n++) { prod[n] = 1.0f; hs[n] = 0.0f; }
    for (int lrr = 0; lrr < LC; lrr++) {
        int row = base_row + lrr;
        float dl = bf2f(delta[(size_t)row * D_INNER + d]);
        float uu = bf2f(u[(size_t)row * D_INNER + d]);
        float du = dl * uu;
        #pragma unroll
        for (int n = 0; n < 8; n++) {
            float dA = __expf(dl * Ad[n]);
            prod[n] *= dA;
            hs[n] = dA * hs[n] + du * bc[lrr][n];
        }
    }
    size_t o = ((size_t)((size_t)b * NC + c) * D_INNER + d) * 8;
    u16x8 po, so;
    #pragma unroll
    for (int n = 0; n < 8; n++) { po[n] = f2bf(prod[n]); so[n] = f2bf(hs[n]); }
    *(u16x8*)(P + o) = po;
    *(u16x8*)(S + o) = so;
}

// ---------------- scan: pass B (bf16 in, bf16 hstart out; f32 accumulate) ----------------
__global__ __launch_bounds__(256) void scan_passB(const unsigned short* __restrict__ P,
                                                  const unsigned short* __restrict__ S,
                                                  unsigned short* __restrict__ hstart) {
    int tid = blockIdx.x * 256 + threadIdx.x;
    int b = tid / (D_INNER * 8);
    int rem = tid % (D_INNER * 8);
    float h = 0.0f;
    for (int c = 0; c < NC; c++) {
        size_t o = (size_t)(b * NC + c) * (D_INNER * 8) + rem;
        hstart[o] = f2bf(h);
        h = bf2f(P[o]) * h + bf2f(S[o]);
    }
}

// ---------------- scan: pass C -> bf16 ygate (bf16 hstart in) ----------------
__global__ __launch_bounds__(256) void scan_passC(const unsigned short* __restrict__ delta,
                                                  const unsigned short* __restrict__ u,
                                                  const unsigned short* __restrict__ xq,
                                                  const float* __restrict__ A_log,
                                                  const unsigned short* __restrict__ hstart,
                                                  const unsigned short* __restrict__ xz,
                                                  const float* __restrict__ Dp,
                                                  unsigned short* __restrict__ ygate) {
    int d = blockIdx.x * 256 + threadIdx.x;
    int c = blockIdx.y, b = blockIdx.z;
    __shared__ float bc[LC][16];
    int base_row = b * SEQ + c * LC;
    for (int e = threadIdx.x; e < LC * 16; e += 256) {
        int lrr = e >> 4, col = e & 15;
        const unsigned short* xr = xq + (size_t)(base_row + lrr) * XQW + 64 + col;
        bc[lrr][col] = bf2f(xr[0]) + bf2f(xr[128]) + bf2f(xr[256]) + bf2f(xr[384]);
    }
    __syncthreads();
    float Ad[8];
    #pragma unroll
    for (int n = 0; n < 8; n++) Ad[n] = -__expf(A_log[d * 8 + n]);
    float h[8];
    size_t ho = ((size_t)((size_t)b * NC + c) * D_INNER + d) * 8;
    u16x8 hv = *(const u16x8*)(hstart + ho);
    #pragma unroll
    for (int n = 0; n < 8; n++) h[n] = bf2f((unsigned short)hv[n]);
    float Dd = Dp[d];
    for (int lrr = 0; lrr < LC; lrr++) {
        int row = base_row + lrr;
        float dl = bf2f(delta[(size_t)row * D_INNER + d]);
        float uu = bf2f(u[(size_t)row * D_INNER + d]);
        float du = dl * uu;
        float y = 0.0f;
        #pragma unroll
        for (int n = 0; n < 8; n++) {
            float dA = __expf(dl * Ad[n]);
            h[n] = dA * h[n] + du * bc[lrr][n];
            y += h[n] * bc[lrr][8 + n];
        }
        y += uu * Dd;
        float z = bf2f(xz[(size_t)row * (2 * D_INNER) + D_INNER + d]);
        ygate[(size_t)row * D_INNER + d] = f2bf(y * silu_f(z));
    }
}

// ---------------- launch ----------------
extern "C" void kernel_launch(void* const* d_in, const int* in_sizes, int n_in,
                              void* d_out, int out_size, void* d_ws, size_t ws_size,
                              hipStream_t stream) {
    const float* x         = (const float*)d_in[0];
    const float* ln1_g     = (const float*)d_in[1];
    const float* ln1_b     = (const float*)d_in[2];
    const float* ln2_g     = (const float*)d_in[3];
    const float* ln2_b     = (const float*)d_in[4];
    const float* in_proj_w = (const float*)d_in[5];
    const float* conv_w    = (const float*)d_in[6];
    const float* conv_b    = (const float*)d_in[7];
    const float* x_proj_w  = (const float*)d_in[8];
    const float* dt_proj_w = (const float*)d_in[9];
    const float* dt_proj_b = (const float*)d_in[10];
    const float* A_log     = (const float*)d_in[11];
    const float* Dp        = (const float*)d_in[12];
    const float* out_proj_w= (const float*)d_in[13];
    const float* ffn_w1    = (const float*)d_in[14];
    const float* ffn_b1    = (const float*)d_in[15];
    const float* ffn_w2    = (const float*)d_in[16];
    const float* ffn_b2    = (const float*)d_in[17];
    float* out = (float*)d_out;

    // ---- workspace layout ----
    const size_t SCN = (size_t)BATCH * NC * D_INNER * 8;    // 786432 elements
    unsigned short* P   = (unsigned short*)d_ws;            // bf16 scan state
    unsigned short* S   = P + SCN;
    unsigned short* hst = S + SCN;
    float* x2    = (float*)(hst + SCN + SCN);               // 4096*1024 f32
    unsigned short* psum_bf = (unsigned short*)(x2 + (size_t)NROWS * D_MODEL);     // 2*4096*1024 bf16
    unsigned short* xq      = psum_bf + 2 * (size_t)NROWS * D_MODEL;               // 4096*512 bf16
    unsigned short* xz_bf   = xq + (size_t)NROWS * XQW;              // 4096*3072
    unsigned short* xp_bf   = xz_bf + (size_t)NROWS * 2 * D_INNER;   // 4096*1024 (reused as xn_bf)
    unsigned short* u_bf    = xp_bf + (size_t)NROWS * D_MODEL;       // 4096*1536
    unsigned short* yg_bf   = u_bf + (size_t)NROWS * D_INNER;        // 4096*1536
    unsigned short* dl_bf   = yg_bf + (size_t)NROWS * D_INNER;       // 4096*1536
    unsigned short* w_in    = dl_bf + (size_t)NROWS * D_INNER;       // 3072*1024
    unsigned short* w_xp    = w_in + (size_t)2 * D_INNER * D_MODEL;  // 128*1536
    unsigned short* w_dt    = w_xp + (size_t)128 * D_INNER;          // 1536*64
    unsigned short* w_out   = w_dt + (size_t)D_INNER * DT_RANK;      // 1024*1536
    unsigned short* w_f1    = w_out + (size_t)D_MODEL * D_INNER;     // 2048*1024
    unsigned short* w_f2    = w_f1 + (size_t)D_FF * D_MODEL;         // 1024*2048
    unsigned short* hff_bf  = xz_bf;   // overlay: xz dead after scan_passC

    // 1. prep: weight conversions + x_proj pad + LN1
    prep_kernel<<<4528 + NROWS, 256, 0, stream>>>(
        in_proj_w, w_in, dt_proj_w, w_dt, out_proj_w, w_out, ffn_w1, w_f1, ffn_w2, w_f2,
        x_proj_w, w_xp, x, ln1_g, ln1_b, xp_bf);
    // 2. in_proj (4096 x 3072, K=1024) -> bf16   [8-phase 256x256]
    gemm8p<4, EPI_BF16, 1, 8><<<dim3(3072 / 256, NROWS / 256), 512, 0, stream>>>(
        xp_bf, D_MODEL, w_in, D_MODEL, D_MODEL, nullptr, xz_bf, 2 * D_INNER, nullptr, nullptr, 0);
    // 3. fused conv+silu+x_proj: u (bf16) + xq bf16 partials (4096 x 4x128)
    xproj_conv_gemm<<<dim3(NROWS / 128, 4), 256, 0, stream>>>(
        xz_bf, conv_w, conv_b, u_bf, w_xp, xq);
    // 4. fused dt_proj + softplus (A = 4-way xq sum, K=64) -> delta bf16
    dt_fused<<<dim3(D_INNER / 128, NROWS / 128), 256, 0, stream>>>(
        xq, w_dt, dt_proj_b, dl_bf);
    // 5-7. selective scan (bf16 state)
    scan_passA<<<dim3(D_INNER / 256, NC, BATCH), 256, 0, stream>>>(dl_bf, u_bf, xq, A_log, P, S);
    scan_passB<<<(BATCH * D_INNER * 8) / 256, 256, 0, stream>>>(P, S, hst);
    scan_passC<<<dim3(D_INNER / 256, NC, BATCH), 256, 0, stream>>>(dl_bf, u_bf, xq, A_log, hst, xz_bf, Dp, yg_bf);
    // 8. out_proj split-K=2 (K=768 each) -> bf16 partials  [4-phase 256x128]
    gemm8p<2, EPI_PBF16, 2, 4><<<dim3(D_MODEL / 128, NROWS / 256, 2), 512, 0, stream>>>(
        yg_bf, D_INNER, w_out, D_INNER, D_INNER / 2, nullptr, psum_bf, D_MODEL, nullptr, nullptr, 0);
    // 9. fused bf16 reduce + residual + LN2 -> x2 f32, xn bf16
    sk2_ln<<<NROWS, 256, 0, stream>>>(psum_bf, x, ln2_g, ln2_b, x2, xp_bf);
    // 10. ffn1 + gelu -> bf16 hff  (K=1024)  [4-phase 256x128]
    gemm8p<2, EPI_GELU_BF16, 1, 4><<<dim3(D_FF / 128, NROWS / 256), 512, 0, stream>>>(
        xp_bf, D_MODEL, w_f1, D_MODEL, D_MODEL, nullptr, hff_bf, D_FF, ffn_b1, nullptr, 0);
    // 11. ffn2 split-K=2 (K=1024 each) -> bf16 partials  [4-phase 256x128]
    gemm8p<2, EPI_PBF16, 2, 4><<<dim3(D_MODEL / 128, NROWS / 256, 2), 512, 0, stream>>>(
        hff_bf, D_FF, w_f2, D_FF, D_FF / 2, nullptr, psum_bf, D_MODEL, nullptr, nullptr, 0);
    // 12. final bf16 reduce + bias + residual -> out
    sk2_reduce<<<(NROWS * D_MODEL) / 1024, 256, 0, stream>>>(psum_bf, ffn_b2, x2, out);
}